// Round 7
// baseline (570.953 us; speedup 1.0000x reference)
//
#include <hip/hip_runtime.h>
#include <hip/hip_bf16.h>
#include <hip/hip_fp16.h>

#define N_NODES 50000
#define IN_DIM 768
#define HID 128
#define NCLS 32
#define BSHIFT 5   // 32 nodes per bucket

typedef __attribute__((ext_vector_type(8))) short bf16x8;
typedef __attribute__((ext_vector_type(4))) float f32x4;
typedef __attribute__((ext_vector_type(4))) unsigned short u16x4;

__device__ inline void split_bf16(float x, unsigned short& hi, unsigned short& lo) {
    unsigned int u = __float_as_uint(x);
    hi = (unsigned short)(u >> 16);
    float r = x - __uint_as_float(u & 0xFFFF0000u);
    lo = (unsigned short)(__float_as_uint(r) >> 16);
}

// ---------------- degree count (int32 or int64 edge_index) -------------------
__global__ void count_edges(const int* __restrict__ raw, int E, int* __restrict__ deg) {
    bool is64 = (raw[1] == 0 && raw[3] == 0 && raw[5] == 0 && raw[7] == 0);
    int e = blockIdx.x * blockDim.x + threadIdx.x;
    if (e < E) {
        int d = is64 ? raw[2 * (E + e)] : raw[E + e];
        atomicAdd(&deg[d], 1);
    }
}

__global__ void compute_dinv(const int* __restrict__ deg, float* __restrict__ dinv, int n) {
    int i = blockIdx.x * blockDim.x + threadIdx.x;
    if (i < n) dinv[i] = rsqrtf((float)(deg[i] + 1));  // +1 = self-loop
}

// ---------------- hierarchical exclusive scan (3 kernels) --------------------
__global__ __launch_bounds__(256) void scan_blk_sum(const int* __restrict__ cnt, int n,
                                                    int* __restrict__ bsum) {
    __shared__ int sm[256];
    int gid = blockIdx.x * 256 + threadIdx.x;
    sm[threadIdx.x] = (gid < n) ? cnt[gid] : 0;
    __syncthreads();
    for (int o = 128; o > 0; o >>= 1) {
        if (threadIdx.x < o) sm[threadIdx.x] += sm[threadIdx.x + o];
        __syncthreads();
    }
    if (threadIdx.x == 0) bsum[blockIdx.x] = sm[0];
}

__global__ __launch_bounds__(256) void scan_offsets(int* __restrict__ bsum, int nb,
                                                    int* __restrict__ rowp, int n, int Etot) {
    __shared__ int sm[256];
    int t = threadIdx.x;
    sm[t] = (t < nb) ? bsum[t] : 0;
    __syncthreads();
    for (int o = 1; o < 256; o <<= 1) {
        int v = (t >= o) ? sm[t - o] : 0;
        __syncthreads();
        sm[t] += v;
        __syncthreads();
    }
    if (t < nb) bsum[t] = (t == 0) ? 0 : sm[t - 1];
    if (t == 0) rowp[n] = Etot;
}

__global__ __launch_bounds__(256) void scan_final(const int* __restrict__ cnt, int n,
                                                  const int* __restrict__ bsum,
                                                  int* __restrict__ rowp) {
    __shared__ int sm[256];
    int t = threadIdx.x;
    int gid = blockIdx.x * 256 + t;
    int v = (gid < n) ? cnt[gid] : 0;
    sm[t] = v;
    __syncthreads();
    for (int o = 1; o < 256; o <<= 1) {
        int u = (t >= o) ? sm[t - o] : 0;
        __syncthreads();
        sm[t] += u;
        __syncthreads();
    }
    if (gid < n) rowp[gid] = bsum[blockIdx.x] + sm[t] - v;  // exclusive
}

// ---------------- two-pass locality-staged scatter ---------------------------
// pass 1: bucket by dst>>BSHIFT; bucket base = rowp[b<<BSHIFT] (free!).
// Bucket tails advance sequentially -> L2 merges the int2 writes.
__global__ void bucket_scatter(const int* __restrict__ raw, int E,
                               const int* __restrict__ rowp, int* __restrict__ bfill,
                               int2* __restrict__ ebuf) {
    bool is64 = (raw[1] == 0 && raw[3] == 0 && raw[5] == 0 && raw[7] == 0);
    int e = blockIdx.x * blockDim.x + threadIdx.x;
    if (e < E) {
        int s, d;
        if (is64) { s = raw[2 * e]; d = raw[2 * (E + e)]; }
        else      { s = raw[e];     d = raw[E + e]; }
        int b = d >> BSHIFT;
        int pos = rowp[b << BSHIFT] + atomicAdd(&bfill[b], 1);
        ebuf[pos] = make_int2(s, d);
    }
}

// pass 2: ebuf is bucket-ordered -> each block's csr writes land in a ~4KB
// window -> full L2 line merging, no write amplification.
__global__ void fine_scatter(const int2* __restrict__ ebuf, int E,
                             const int* __restrict__ rowp, int* __restrict__ fill,
                             int* __restrict__ csr) {
    int p = blockIdx.x * blockDim.x + threadIdx.x;
    if (p < E) {
        int2 sd = ebuf[p];
        int q = rowp[sd.y] + atomicAdd(&fill[sd.y], 1);
        csr[q] = sd.x;
    }
}

// ---------------- weight pack: W[K][128] f32 -> fragment-order split bf16 -----
__global__ void pack_w(const float* __restrict__ W, int K,
                       unsigned short* __restrict__ ph, unsigned short* __restrict__ pl) {
    int gid = blockIdx.x * 256 + threadIdx.x;
    int total = (K / 32) * 8 * 64;
    if (gid >= total) return;
    int l = gid & 63;
    int c0 = (gid >> 6) & 7;
    int t = gid >> 9;
    int col = c0 * 16 + (l & 15);
    int k0 = t * 32 + ((l >> 4) << 3);
    size_t base = (size_t)gid * 8;
#pragma unroll
    for (int j = 0; j < 8; ++j) {
        unsigned short h, lo;
        split_bf16(W[(size_t)(k0 + j) * 128 + col], h, lo);
        ph[base + j] = h;
        pl[base + j] = lo;
    }
}

// ---------------- split-bf16 MFMA GEMM: Chalf[M,128] = A[M,K] @ B[K,128] -----
template <int K>
__global__ __launch_bounds__(256) void gemm_mfma2(const float* __restrict__ A,
                                                  const unsigned short* __restrict__ Bph,
                                                  const unsigned short* __restrict__ Bpl,
                                                  __half* __restrict__ Chalf, int M) {
    __shared__ unsigned short Ah[64][40];  // 32 + 8 pad
    __shared__ unsigned short Al[64][40];
    int tid = threadIdx.x;
    int wid = tid >> 6, lane = tid & 63;
    int wr = wid >> 1, wc = wid & 1;      // wave grid 2x2
    int row0 = blockIdx.x * 64;
    int lrow = lane & 15, lk = (lane >> 4) * 8;
    const int T = K / 32;

    int sidx0 = tid, sidx1 = 256 + tid;
    int sr0 = sidx0 >> 3, sc0 = (sidx0 & 7) * 4;
    int sr1 = sidx1 >> 3, sc1 = (sidx1 & 7) * 4;
    bool v0 = (row0 + sr0) < M, v1 = (row0 + sr1) < M;
    const float* a0 = &A[(size_t)(row0 + sr0) * K + sc0];
    const float* a1 = &A[(size_t)(row0 + sr1) * K + sc1];

    float4 pre0 = make_float4(0.f, 0.f, 0.f, 0.f), pre1 = pre0;
    if (v0) pre0 = *(const float4*)a0;
    if (v1) pre1 = *(const float4*)a1;

    f32x4 acc[2][4] = {};
    for (int t = 0; t < T; ++t) {
        u16x4 h, lo;
        split_bf16(pre0.x, ((unsigned short*)&h)[0], ((unsigned short*)&lo)[0]);
        split_bf16(pre0.y, ((unsigned short*)&h)[1], ((unsigned short*)&lo)[1]);
        split_bf16(pre0.z, ((unsigned short*)&h)[2], ((unsigned short*)&lo)[2]);
        split_bf16(pre0.w, ((unsigned short*)&h)[3], ((unsigned short*)&lo)[3]);
        *(u16x4*)&Ah[sr0][sc0] = h;
        *(u16x4*)&Al[sr0][sc0] = lo;
        split_bf16(pre1.x, ((unsigned short*)&h)[0], ((unsigned short*)&lo)[0]);
        split_bf16(pre1.y, ((unsigned short*)&h)[1], ((unsigned short*)&lo)[1]);
        split_bf16(pre1.z, ((unsigned short*)&h)[2], ((unsigned short*)&lo)[2]);
        split_bf16(pre1.w, ((unsigned short*)&h)[3], ((unsigned short*)&lo)[3]);
        *(u16x4*)&Ah[sr1][sc1] = h;
        *(u16x4*)&Al[sr1][sc1] = lo;
        __syncthreads();
        if (t + 1 < T) {
            pre0 = make_float4(0.f, 0.f, 0.f, 0.f); pre1 = pre0;
            if (v0) pre0 = *(const float4*)(a0 + (t + 1) * 32);
            if (v1) pre1 = *(const float4*)(a1 + (t + 1) * 32);
        }
        bf16x8 ah[2], al[2];
#pragma unroll
        for (int m = 0; m < 2; ++m) {
            int r = wr * 32 + m * 16 + lrow;
            ah[m] = *(const bf16x8*)&Ah[r][lk];
            al[m] = *(const bf16x8*)&Al[r][lk];
        }
        bf16x8 bh[4], bl[4];
#pragma unroll
        for (int n = 0; n < 4; ++n) {
            size_t boff = ((size_t)(t * 8 + wc * 4 + n) * 64 + lane) * 8;
            bh[n] = *(const bf16x8*)&Bph[boff];
            bl[n] = *(const bf16x8*)&Bpl[boff];
        }
#pragma unroll
        for (int m = 0; m < 2; ++m)
#pragma unroll
            for (int n = 0; n < 4; ++n) {
                acc[m][n] = __builtin_amdgcn_mfma_f32_16x16x32_bf16(ah[m], bh[n], acc[m][n], 0, 0, 0);
                acc[m][n] = __builtin_amdgcn_mfma_f32_16x16x32_bf16(al[m], bh[n], acc[m][n], 0, 0, 0);
                acc[m][n] = __builtin_amdgcn_mfma_f32_16x16x32_bf16(ah[m], bl[n], acc[m][n], 0, 0, 0);
            }
        __syncthreads();
    }
#pragma unroll
    for (int m = 0; m < 2; ++m) {
        int rbase = row0 + wr * 32 + m * 16 + (lane >> 4) * 4;
#pragma unroll
        for (int n = 0; n < 4; ++n) {
            int col = wc * 64 + n * 16 + lrow;
#pragma unroll
            for (int j = 0; j < 4; ++j) {
                int r = rbase + j;
                if (r < M) Chalf[(size_t)r * 128 + col] = __float2half(acc[m][n][j]);
            }
        }
    }
}

// ---------------- aggregation: wave-per-node, fp16 gather, unroll-8 ----------
__global__ __launch_bounds__(256) void aggregate3(const __half* __restrict__ ht,
                                                  const int* __restrict__ rowp,
                                                  const int* __restrict__ csr,
                                                  const float* __restrict__ dinv,
                                                  const float* __restrict__ bias,
                                                  float* __restrict__ out, int n) {
    int wid = threadIdx.x >> 6, lane = threadIdx.x & 63;
    int i = blockIdx.x * 4 + wid;
    if (i >= n) return;
    const __half2* h2 = (const __half2*)ht;  // [n][64] half2
    float di = dinv[i];
    float2 self = __half22float2(h2[(size_t)i * 64 + lane]);
    float2 acc;
    acc.x = di * di * self.x;
    acc.y = di * di * self.y;
    int b = rowp[i], e = rowp[i + 1];
    int p = b;
    for (; p + 8 <= e; p += 8) {
        int s[8]; float2 v[8]; float nn[8];
#pragma unroll
        for (int q = 0; q < 8; ++q) s[q] = csr[p + q];
#pragma unroll
        for (int q = 0; q < 8; ++q) v[q] = __half22float2(h2[(size_t)s[q] * 64 + lane]);
#pragma unroll
        for (int q = 0; q < 8; ++q) nn[q] = dinv[s[q]] * di;
#pragma unroll
        for (int q = 0; q < 8; ++q) { acc.x += nn[q] * v[q].x; acc.y += nn[q] * v[q].y; }
    }
    for (; p < e; ++p) {
        int s = csr[p];
        float nn = dinv[s] * di;
        float2 v = __half22float2(h2[(size_t)s * 64 + lane]);
        acc.x += nn * v.x;
        acc.y += nn * v.y;
    }
    float2 bb = ((const float2*)bias)[lane];
    float2 o;
    o.x = fmaxf(acc.x + bb.x, 0.f);
    o.y = fmaxf(acc.y + bb.y, 0.f);
    ((float2*)out)[(size_t)i * 64 + lane] = o;
}

// ---------------- final FC: out[N,32] = h[N,128] @ Wfc[128,32] + bfc ---------
__global__ __launch_bounds__(256) void fc_out(const float* __restrict__ h,
                                              const float* __restrict__ W,
                                              const float* __restrict__ b,
                                              float* __restrict__ out, int n) {
    __shared__ float Ws[HID * NCLS];
    __shared__ float Hs[8][HID];
    int tid = threadIdx.x;
#pragma unroll
    for (int l = 0; l < 16; ++l) Ws[l * 256 + tid] = W[l * 256 + tid];
    int row0 = blockIdx.x * 8;
#pragma unroll
    for (int l = 0; l < 4; ++l) {
        int idx = l * 256 + tid;
        int r = idx >> 7, c = idx & 127;
        int gr = row0 + r;
        Hs[r][c] = (gr < n) ? h[(size_t)gr * HID + c] : 0.f;
    }
    __syncthreads();
    int r = tid >> 5, c = tid & 31;
    float acc = b[c];
#pragma unroll
    for (int k = 0; k < HID; ++k) acc += Hs[r][k] * Ws[k * NCLS + c];
    int gr = row0 + r;
    if (gr < n) out[(size_t)gr * NCLS + c] = acc;
}

extern "C" void kernel_launch(void* const* d_in, const int* in_sizes, int n_in,
                              void* d_out, int out_size, void* d_ws, size_t ws_size,
                              hipStream_t stream) {
    const float* x   = (const float*)d_in[0];
    const int*   eid = (const int*)d_in[1];
    const float* W1  = (const float*)d_in[2];
    const float* b1  = (const float*)d_in[3];
    const float* W2  = (const float*)d_in[4];
    const float* b2  = (const float*)d_in[5];
    const float* Wfc = (const float*)d_in[6];
    const float* bfc = (const float*)d_in[7];
    float* out = (float*)d_out;

    const int N = N_NODES;
    const int E = in_sizes[1] / 2;
    const int NB1 = (N + 255) / 256;
    const int NBUCK = (N + (1 << BSHIFT) - 1) >> BSHIFT;  // 1563

    auto align = [](size_t v) { return (v + 255) & ~(size_t)255; };
    char* w = (char*)d_ws;
    size_t off = 0;
    int* deg = (int*)(w + off);            off += (size_t)N * 4;      // deg+fill+bfill contiguous
    int* fill = (int*)(w + off);           off += (size_t)N * 4;
    int* bfill = (int*)(w + off);          off = align(off + (size_t)NBUCK * 4);
    int* rowp = (int*)(w + off);           off = align(off + (size_t)(N + 1) * 4);
    float* dinv = (float*)(w + off);       off = align(off + (size_t)N * 4);
    int* csr = (int*)(w + off);            off = align(off + (size_t)E * 4);
    int2* ebuf = (int2*)(w + off);         off = align(off + (size_t)E * 8);
    int* bsum = (int*)(w + off);           off = align(off + (size_t)NB1 * 4);
    unsigned short* W1ph = (unsigned short*)(w + off); off = align(off + (size_t)128 * IN_DIM * 2);
    unsigned short* W1pl = (unsigned short*)(w + off); off = align(off + (size_t)128 * IN_DIM * 2);
    unsigned short* W2ph = (unsigned short*)(w + off); off = align(off + (size_t)128 * HID * 2);
    unsigned short* W2pl = (unsigned short*)(w + off); off = align(off + (size_t)128 * HID * 2);
    __half* h1 = (__half*)(w + off);       off = align(off + (size_t)N * HID * 2);
    __half* h2t = (__half*)(w + off);      off = align(off + (size_t)N * HID * 2);
    float* bufA = (float*)(w + off);       off = align(off + (size_t)N * HID * 4);
    float* bufB = (float*)(w + off);       off = align(off + (size_t)N * HID * 4);

    int eb = (E + 255) / 256;
    hipMemsetAsync(deg, 0, ((size_t)2 * N + NBUCK) * 4, stream);  // deg + fill + bfill
    count_edges<<<eb, 256, 0, stream>>>(eid, E, deg);
    compute_dinv<<<(N + 255) / 256, 256, 0, stream>>>(deg, dinv, N);
    scan_blk_sum<<<NB1, 256, 0, stream>>>(deg, N, bsum);
    scan_offsets<<<1, 256, 0, stream>>>(bsum, NB1, rowp, N, E);
    scan_final<<<NB1, 256, 0, stream>>>(deg, N, bsum, rowp);
    bucket_scatter<<<eb, 256, 0, stream>>>(eid, E, rowp, bfill, ebuf);
    fine_scatter<<<eb, 256, 0, stream>>>(ebuf, E, rowp, fill, csr);

    pack_w<<<((IN_DIM / 32) * 8 * 64 + 255) / 256, 256, 0, stream>>>(W1, IN_DIM, W1ph, W1pl);
    pack_w<<<((HID / 32) * 8 * 64 + 255) / 256, 256, 0, stream>>>(W2, HID, W2ph, W2pl);

    int gb = (N + 63) / 64;
    gemm_mfma2<IN_DIM><<<gb, 256, 0, stream>>>(x, W1ph, W1pl, h1, N);
    aggregate3<<<(N + 3) / 4, 256, 0, stream>>>(h1, rowp, csr, dinv, b1, bufA, N);
    gemm_mfma2<HID><<<gb, 256, 0, stream>>>(bufA, W2ph, W2pl, h2t, N);
    aggregate3<<<(N + 3) / 4, 256, 0, stream>>>(h2t, rowp, csr, dinv, b2, bufB, N);
    fc_out<<<(N + 7) / 8, 256, 0, stream>>>(bufB, Wfc, bfc, out, N);
}

// Round 9
// 375.961 us; speedup vs baseline: 1.5187x; 1.5187x over previous
//
#include <hip/hip_runtime.h>
#include <hip/hip_bf16.h>
#include <hip/hip_fp16.h>

#define N_NODES 50000
#define IN_DIM 768
#define HID 128
#define NCLS 32
#define CHUNK 8192                       // edges per chunk-block
#define NBUCK ((N_NODES + 255) >> 8)     // 196 coarse buckets (256 nodes each)

typedef __attribute__((ext_vector_type(8))) short bf16x8;
typedef __attribute__((ext_vector_type(4))) float f32x4;
typedef __attribute__((ext_vector_type(4))) unsigned short u16x4;

__device__ inline void split_bf16(float x, unsigned short& hi, unsigned short& lo) {
    unsigned int u = __float_as_uint(x);
    hi = (unsigned short)(u >> 16);
    float r = x - __uint_as_float(u & 0xFFFF0000u);
    lo = (unsigned short)(__float_as_uint(r) >> 16);
}

// ---------------- pass 1: degree count (global) + coarse LDS histogram -------
__global__ __launch_bounds__(256) void count_hist(const int* __restrict__ raw, int E,
                                                  int* __restrict__ deg,
                                                  int* __restrict__ hist) {
    __shared__ int cnt[NBUCK];
    bool is64 = (raw[1] == 0 && raw[3] == 0 && raw[5] == 0 && raw[7] == 0);
    int t = threadIdx.x, b = blockIdx.x;
    if (t < NBUCK) cnt[t] = 0;
    __syncthreads();
    int base = b * CHUNK;
#pragma unroll
    for (int j = 0; j < CHUNK / 256; ++j) {
        int e = base + j * 256 + t;
        if (e < E) {
            int d = is64 ? raw[2 * (E + e)] : raw[E + e];
            atomicAdd(&deg[d], 1);
            atomicAdd(&cnt[d >> 8], 1);
        }
    }
    __syncthreads();
    if (t < NBUCK) hist[b * NBUCK + t] = cnt[t];
}

__global__ void compute_dinv(const int* __restrict__ deg, float* __restrict__ dinv, int n) {
    int i = blockIdx.x * blockDim.x + threadIdx.x;
    if (i < n) dinv[i] = rsqrtf((float)(deg[i] + 1));  // +1 = self-loop
}

// ---------------- hierarchical exclusive scan for rowp -----------------------
__global__ __launch_bounds__(256) void scan_blk_sum(const int* __restrict__ cnt, int n,
                                                    int* __restrict__ bsum) {
    __shared__ int sm[256];
    int gid = blockIdx.x * 256 + threadIdx.x;
    sm[threadIdx.x] = (gid < n) ? cnt[gid] : 0;
    __syncthreads();
    for (int o = 128; o > 0; o >>= 1) {
        if (threadIdx.x < o) sm[threadIdx.x] += sm[threadIdx.x + o];
        __syncthreads();
    }
    if (threadIdx.x == 0) bsum[blockIdx.x] = sm[0];
}

__global__ __launch_bounds__(256) void scan_offsets(int* __restrict__ bsum, int nb,
                                                    int* __restrict__ rowp, int n, int Etot) {
    __shared__ int sm[256];
    int t = threadIdx.x;
    sm[t] = (t < nb) ? bsum[t] : 0;
    __syncthreads();
    for (int o = 1; o < 256; o <<= 1) {
        int v = (t >= o) ? sm[t - o] : 0;
        __syncthreads();
        sm[t] += v;
        __syncthreads();
    }
    if (t < nb) bsum[t] = (t == 0) ? 0 : sm[t - 1];
    if (t == 0) rowp[n] = Etot;
}

__global__ __launch_bounds__(256) void scan_final(const int* __restrict__ cnt, int n,
                                                  const int* __restrict__ bsum,
                                                  int* __restrict__ rowp) {
    __shared__ int sm[256];
    int t = threadIdx.x;
    int gid = blockIdx.x * 256 + t;
    int v = (gid < n) ? cnt[gid] : 0;
    sm[t] = v;
    __syncthreads();
    for (int o = 1; o < 256; o <<= 1) {
        int u = (t >= o) ? sm[t - o] : 0;
        __syncthreads();
        sm[t] += u;
        __syncthreads();
    }
    if (gid < n) rowp[gid] = bsum[blockIdx.x] + sm[t] - v;  // exclusive
}

// ---------------- pass 2: per-(block,bucket) offsets -------------------------
// off[b][k] = rowp[k<<8] + sum_{b'<b} hist[b'][k]
__global__ __launch_bounds__(256) void scan_off(const int* __restrict__ hist, int nblk,
                                                const int* __restrict__ rowp,
                                                int* __restrict__ off) {
    int t = threadIdx.x;
    if (t >= NBUCK) return;
    int run = rowp[t << 8];
    for (int b = 0; b < nblk; ++b) {
        off[b * NBUCK + t] = run;
        run += hist[b * NBUCK + t];
    }
}

// ---------------- pass 3: chunk scatter into bucket-sorted ebuf (LDS rank) ---
__global__ __launch_bounds__(256) void chunk_scatter(const int* __restrict__ raw, int E,
                                                     const int* __restrict__ off,
                                                     int2* __restrict__ ebuf) {
    __shared__ int offl[NBUCK];
    __shared__ int cnt[NBUCK];
    bool is64 = (raw[1] == 0 && raw[3] == 0 && raw[5] == 0 && raw[7] == 0);
    int t = threadIdx.x, b = blockIdx.x;
    if (t < NBUCK) { offl[t] = off[b * NBUCK + t]; cnt[t] = 0; }
    __syncthreads();
    int base = b * CHUNK;
#pragma unroll
    for (int j = 0; j < CHUNK / 256; ++j) {
        int e = base + j * 256 + t;
        if (e < E) {
            int s, d;
            if (is64) { s = raw[2 * e]; d = raw[2 * (E + e)]; }
            else      { s = raw[e];     d = raw[E + e]; }
            int k = d >> 8;
            int r = atomicAdd(&cnt[k], 1);
            ebuf[offl[k] + r] = make_int2(s, d);
        }
    }
}

// ---------------- pass 4: per-bucket fine scatter (single-owner window) ------
__global__ __launch_bounds__(256) void bucket_fine(const int2* __restrict__ ebuf,
                                                   const int* __restrict__ rowp,
                                                   int* __restrict__ csr, int n) {
    __shared__ int rowp_l[256];
    __shared__ int fill_l[256];
    int k = blockIdx.x, t = threadIdx.x;
    int base = k << 8;
    int nn = min(256, n - base);
    if (t < nn) { rowp_l[t] = rowp[base + t]; fill_l[t] = 0; }
    __syncthreads();
    int estart = rowp[base];
    int eend = rowp[base + nn];
    for (int p = estart + t; p < eend; p += 256) {
        int2 sd = ebuf[p];
        int local = sd.y - base;
        int q = rowp_l[local] + atomicAdd(&fill_l[local], 1);
        csr[q] = sd.x;
    }
}

// ---------------- weight pack: W[K][128] f32 -> fragment-order split bf16 -----
__global__ void pack_w(const float* __restrict__ W, int K,
                       unsigned short* __restrict__ ph, unsigned short* __restrict__ pl) {
    int gid = blockIdx.x * 256 + threadIdx.x;
    int total = (K / 32) * 8 * 64;
    if (gid >= total) return;
    int l = gid & 63;
    int c0 = (gid >> 6) & 7;
    int t = gid >> 9;
    int col = c0 * 16 + (l & 15);
    int k0 = t * 32 + ((l >> 4) << 3);
    size_t base = (size_t)gid * 8;
#pragma unroll
    for (int j = 0; j < 8; ++j) {
        unsigned short h, lo;
        split_bf16(W[(size_t)(k0 + j) * 128 + col], h, lo);
        ph[base + j] = h;
        pl[base + j] = lo;
    }
}

// ---------------- split-bf16 MFMA GEMM: Chalf[M,128] = A[M,K] @ B[K,128] -----
template <int K>
__global__ __launch_bounds__(256) void gemm_mfma2(const float* __restrict__ A,
                                                  const unsigned short* __restrict__ Bph,
                                                  const unsigned short* __restrict__ Bpl,
                                                  __half* __restrict__ Chalf, int M) {
    __shared__ unsigned short Ah[64][40];  // 32 + 8 pad
    __shared__ unsigned short Al[64][40];
    int tid = threadIdx.x;
    int wid = tid >> 6, lane = tid & 63;
    int wr = wid >> 1, wc = wid & 1;      // wave grid 2x2
    int row0 = blockIdx.x * 64;
    int lrow = lane & 15, lk = (lane >> 4) * 8;
    const int T = K / 32;

    int sidx0 = tid, sidx1 = 256 + tid;
    int sr0 = sidx0 >> 3, sc0 = (sidx0 & 7) * 4;
    int sr1 = sidx1 >> 3, sc1 = (sidx1 & 7) * 4;
    bool v0 = (row0 + sr0) < M, v1 = (row0 + sr1) < M;
    const float* a0 = &A[(size_t)(row0 + sr0) * K + sc0];
    const float* a1 = &A[(size_t)(row0 + sr1) * K + sc1];

    float4 pre0 = make_float4(0.f, 0.f, 0.f, 0.f), pre1 = pre0;
    if (v0) pre0 = *(const float4*)a0;
    if (v1) pre1 = *(const float4*)a1;

    f32x4 acc[2][4] = {};
    for (int t = 0; t < T; ++t) {
        u16x4 h, lo;
        split_bf16(pre0.x, ((unsigned short*)&h)[0], ((unsigned short*)&lo)[0]);
        split_bf16(pre0.y, ((unsigned short*)&h)[1], ((unsigned short*)&lo)[1]);
        split_bf16(pre0.z, ((unsigned short*)&h)[2], ((unsigned short*)&lo)[2]);
        split_bf16(pre0.w, ((unsigned short*)&h)[3], ((unsigned short*)&lo)[3]);
        *(u16x4*)&Ah[sr0][sc0] = h;
        *(u16x4*)&Al[sr0][sc0] = lo;
        split_bf16(pre1.x, ((unsigned short*)&h)[0], ((unsigned short*)&lo)[0]);
        split_bf16(pre1.y, ((unsigned short*)&h)[1], ((unsigned short*)&lo)[1]);
        split_bf16(pre1.z, ((unsigned short*)&h)[2], ((unsigned short*)&lo)[2]);
        split_bf16(pre1.w, ((unsigned short*)&h)[3], ((unsigned short*)&lo)[3]);
        *(u16x4*)&Ah[sr1][sc1] = h;
        *(u16x4*)&Al[sr1][sc1] = lo;
        __syncthreads();
        if (t + 1 < T) {
            pre0 = make_float4(0.f, 0.f, 0.f, 0.f); pre1 = pre0;
            if (v0) pre0 = *(const float4*)(a0 + (t + 1) * 32);
            if (v1) pre1 = *(const float4*)(a1 + (t + 1) * 32);
        }
        bf16x8 ah[2], al[2];
#pragma unroll
        for (int m = 0; m < 2; ++m) {
            int r = wr * 32 + m * 16 + lrow;
            ah[m] = *(const bf16x8*)&Ah[r][lk];
            al[m] = *(const bf16x8*)&Al[r][lk];
        }
        bf16x8 bh[4], bl[4];
#pragma unroll
        for (int n = 0; n < 4; ++n) {
            size_t boff = ((size_t)(t * 8 + wc * 4 + n) * 64 + lane) * 8;
            bh[n] = *(const bf16x8*)&Bph[boff];
            bl[n] = *(const bf16x8*)&Bpl[boff];
        }
#pragma unroll
        for (int m = 0; m < 2; ++m)
#pragma unroll
            for (int n = 0; n < 4; ++n) {
                acc[m][n] = __builtin_amdgcn_mfma_f32_16x16x32_bf16(ah[m], bh[n], acc[m][n], 0, 0, 0);
                acc[m][n] = __builtin_amdgcn_mfma_f32_16x16x32_bf16(al[m], bh[n], acc[m][n], 0, 0, 0);
                acc[m][n] = __builtin_amdgcn_mfma_f32_16x16x32_bf16(ah[m], bl[n], acc[m][n], 0, 0, 0);
            }
        __syncthreads();
    }
#pragma unroll
    for (int m = 0; m < 2; ++m) {
        int rbase = row0 + wr * 32 + m * 16 + (lane >> 4) * 4;
#pragma unroll
        for (int n = 0; n < 4; ++n) {
            int col = wc * 64 + n * 16 + lrow;
#pragma unroll
            for (int j = 0; j < 4; ++j) {
                int r = rbase + j;
                if (r < M) Chalf[(size_t)r * 128 + col] = __float2half(acc[m][n][j]);
            }
        }
    }
}

// ---------------- aggregation: wave-per-node, fp16 gather, unroll-8 ----------
__global__ __launch_bounds__(256) void aggregate3(const __half* __restrict__ ht,
                                                  const int* __restrict__ rowp,
                                                  const int* __restrict__ csr,
                                                  const float* __restrict__ dinv,
                                                  const float* __restrict__ bias,
                                                  float* __restrict__ out, int n) {
    int wid = threadIdx.x >> 6, lane = threadIdx.x & 63;
    int i = blockIdx.x * 4 + wid;
    if (i >= n) return;
    const __half2* h2 = (const __half2*)ht;  // [n][64] half2
    float di = dinv[i];
    float2 self = __half22float2(h2[(size_t)i * 64 + lane]);
    float2 acc;
    acc.x = di * di * self.x;
    acc.y = di * di * self.y;
    int b = rowp[i], e = rowp[i + 1];
    int p = b;
    for (; p + 8 <= e; p += 8) {
        int s[8]; float2 v[8]; float nn[8];
#pragma unroll
        for (int q = 0; q < 8; ++q) s[q] = csr[p + q];
#pragma unroll
        for (int q = 0; q < 8; ++q) v[q] = __half22float2(h2[(size_t)s[q] * 64 + lane]);
#pragma unroll
        for (int q = 0; q < 8; ++q) nn[q] = dinv[s[q]] * di;
#pragma unroll
        for (int q = 0; q < 8; ++q) { acc.x += nn[q] * v[q].x; acc.y += nn[q] * v[q].y; }
    }
    for (; p < e; ++p) {
        int s = csr[p];
        float nn = dinv[s] * di;
        float2 v = __half22float2(h2[(size_t)s * 64 + lane]);
        acc.x += nn * v.x;
        acc.y += nn * v.y;
    }
    float2 bb = ((const float2*)bias)[lane];
    float2 o;
    o.x = fmaxf(acc.x + bb.x, 0.f);
    o.y = fmaxf(acc.y + bb.y, 0.f);
    ((float2*)out)[(size_t)i * 64 + lane] = o;
}

// ---------------- final FC: out[N,32] = h[N,128] @ Wfc[128,32] + bfc ---------
__global__ __launch_bounds__(256) void fc_out(const float* __restrict__ h,
                                              const float* __restrict__ W,
                                              const float* __restrict__ b,
                                              float* __restrict__ out, int n) {
    __shared__ float Ws[HID * NCLS];
    __shared__ float Hs[8][HID];
    int tid = threadIdx.x;
#pragma unroll
    for (int l = 0; l < 16; ++l) Ws[l * 256 + tid] = W[l * 256 + tid];
    int row0 = blockIdx.x * 8;
#pragma unroll
    for (int l = 0; l < 4; ++l) {
        int idx = l * 256 + tid;
        int r = idx >> 7, c = idx & 127;
        int gr = row0 + r;
        Hs[r][c] = (gr < n) ? h[(size_t)gr * HID + c] : 0.f;
    }
    __syncthreads();
    int r = tid >> 5, c = tid & 31;
    float acc = b[c];
#pragma unroll
    for (int k = 0; k < HID; ++k) acc += Hs[r][k] * Ws[k * NCLS + c];
    int gr = row0 + r;
    if (gr < n) out[(size_t)gr * NCLS + c] = acc;
}

extern "C" void kernel_launch(void* const* d_in, const int* in_sizes, int n_in,
                              void* d_out, int out_size, void* d_ws, size_t ws_size,
                              hipStream_t stream) {
    const float* x   = (const float*)d_in[0];
    const int*   eid = (const int*)d_in[1];
    const float* W1  = (const float*)d_in[2];
    const float* b1  = (const float*)d_in[3];
    const float* W2  = (const float*)d_in[4];
    const float* b2  = (const float*)d_in[5];
    const float* Wfc = (const float*)d_in[6];
    const float* bfc = (const float*)d_in[7];
    float* out = (float*)d_out;

    const int N = N_NODES;
    const int E = in_sizes[1] / 2;
    const int NB1 = (N + 255) / 256;
    const int NBLK = (E + CHUNK - 1) / CHUNK;

    auto align = [](size_t v) { return (v + 255) & ~(size_t)255; };
    char* w = (char*)d_ws;
    size_t off = 0;
    int* deg = (int*)(w + off);            off = align(off + (size_t)N * 4);
    int* rowp = (int*)(w + off);           off = align(off + (size_t)(N + 1) * 4);
    float* dinv = (float*)(w + off);       off = align(off + (size_t)N * 4);
    int* csr = (int*)(w + off);            off = align(off + (size_t)E * 4);
    int2* ebuf = (int2*)(w + off);         off = align(off + (size_t)E * 8);
    int* bsum = (int*)(w + off);           off = align(off + (size_t)NB1 * 4);
    int* hist = (int*)(w + off);           off = align(off + (size_t)NBLK * NBUCK * 4);
    int* offs = (int*)(w + off);           off = align(off + (size_t)NBLK * NBUCK * 4);
    unsigned short* W1ph = (unsigned short*)(w + off); off = align(off + (size_t)128 * IN_DIM * 2);
    unsigned short* W1pl = (unsigned short*)(w + off); off = align(off + (size_t)128 * IN_DIM * 2);
    unsigned short* W2ph = (unsigned short*)(w + off); off = align(off + (size_t)128 * HID * 2);
    unsigned short* W2pl = (unsigned short*)(w + off); off = align(off + (size_t)128 * HID * 2);
    __half* h1 = (__half*)(w + off);       off = align(off + (size_t)N * HID * 2);
    __half* h2t = (__half*)(w + off);      off = align(off + (size_t)N * HID * 2);
    float* bufA = (float*)(w + off);       off = align(off + (size_t)N * HID * 4);
    float* bufB = (float*)(w + off);       off = align(off + (size_t)N * HID * 4);

    hipMemsetAsync(deg, 0, (size_t)N * 4, stream);
    count_hist<<<NBLK, 256, 0, stream>>>(eid, E, deg, hist);
    compute_dinv<<<(N + 255) / 256, 256, 0, stream>>>(deg, dinv, N);
    scan_blk_sum<<<NB1, 256, 0, stream>>>(deg, N, bsum);
    scan_offsets<<<1, 256, 0, stream>>>(bsum, NB1, rowp, N, E);
    scan_final<<<NB1, 256, 0, stream>>>(deg, N, bsum, rowp);
    scan_off<<<1, 256, 0, stream>>>(hist, NBLK, rowp, offs);
    chunk_scatter<<<NBLK, 256, 0, stream>>>(eid, E, offs, ebuf);
    bucket_fine<<<NBUCK, 256, 0, stream>>>(ebuf, rowp, csr, N);

    pack_w<<<((IN_DIM / 32) * 8 * 64 + 255) / 256, 256, 0, stream>>>(W1, IN_DIM, W1ph, W1pl);
    pack_w<<<((HID / 32) * 8 * 64 + 255) / 256, 256, 0, stream>>>(W2, HID, W2ph, W2pl);

    int gb = (N + 63) / 64;
    gemm_mfma2<IN_DIM><<<gb, 256, 0, stream>>>(x, W1ph, W1pl, h1, N);
    aggregate3<<<(N + 3) / 4, 256, 0, stream>>>(h1, rowp, csr, dinv, b1, bufA, N);
    gemm_mfma2<HID><<<gb, 256, 0, stream>>>(bufA, W2ph, W2pl, h2t, N);
    aggregate3<<<(N + 3) / 4, 256, 0, stream>>>(h2t, rowp, csr, dinv, b2, bufB, N);
    fc_out<<<(N + 7) / 8, 256, 0, stream>>>(bufB, Wfc, bfc, out, N);
}